// Round 2
// baseline (3284.623 us; speedup 1.0000x reference)
//
#include <hip/hip_runtime.h>

typedef unsigned short u16;
typedef unsigned int   u32;
typedef unsigned long long u64;
typedef short v8s __attribute__((ext_vector_type(8)));
typedef float v16f __attribute__((ext_vector_type(16)));
typedef float v2f  __attribute__((ext_vector_type(2)));

#define B_ 512
#define I_ 128
#define H_ 512
#define KK 640
#define NSTEP 512
#define AST 648   // A-tile row stride, u16 elems (1296 B = 324 dw, 324%32=4 -> even bank spread)

__device__ inline u16 f2b(float x){
  union{float f; unsigned u;} v; v.f = x;
  unsigned r = v.u + 0x7fffu + ((v.u >> 16) & 1u);
  return (u16)(r >> 16);
}

// overflow-safe fast tanh: x->+inf => 1, x->-inf => -1 (exp underflow)
__device__ inline float tanh_fast(float x){
  float e = __expf(2.f * x);
  return 1.f - 2.f / (e + 1.f);
}

// All cross-wg traffic: relaxed agent-scope atomics -> L3 = coherence point.
__device__ inline u64 ld64(const u16* p){
  return __hip_atomic_load((const u64*)p, __ATOMIC_RELAXED, __HIP_MEMORY_SCOPE_AGENT);
}
__device__ inline void st32(u16* p, u32 v){
  __hip_atomic_store((u32*)p, v, __ATOMIC_RELAXED, __HIP_MEMORY_SCOPE_AGENT);
}
__device__ inline u32 fpoll(const u32* p){
  return __hip_atomic_load(p, __ATOMIC_RELAXED, __HIP_MEMORY_SCOPE_AGENT);
}
__device__ inline void fst(u32* p, u32 v){
  __hip_atomic_store(p, v, __ATOMIC_RELAXED, __HIP_MEMORY_SCOPE_AGENT);
}

// Prep: Wcat[gcol][k] = [W_hh (k<512) | W_ih (k>=512)] bf16, fcW bf16, fused
// bias, h0 bf16, out0 = x[511] bf16, zeroed flags. Re-runs every call.
__global__ void init_kernel(const float* __restrict__ x, const float* __restrict__ h0,
    const float* __restrict__ Wih, const float* __restrict__ Whh,
    const float* __restrict__ bih, const float* __restrict__ bhh, const float* __restrict__ fcW,
    u16* __restrict__ Wcat, u16* __restrict__ fcWb, float* __restrict__ bsum,
    u16* __restrict__ hb0, u16* __restrict__ outb, u32* __restrict__ flags)
{
  int idx = blockIdx.x * 256 + threadIdx.x;
  if (idx < 1310720) {                       // Wcat: 2048 x 640, [Whh | Wih]
    int g = idx / 640, k = idx - g * 640;
    float v = (k < 512) ? Whh[g * 512 + k] : Wih[g * 128 + (k - 512)];
    Wcat[idx] = f2b(v);
  } else if (idx < 1376256) {                // fcW bf16: 128 x 512
    int i = idx - 1310720; fcWb[i] = f2b(fcW[i]);
  } else if (idx < 1378304) {                // fused bias: 2048
    int i = idx - 1376256; bsum[i] = bih[i] + bhh[i];
  } else if (idx < 1640448) {                // h init: 512 x 512
    int i = idx - 1378304; hb0[i] = f2b(h0[i]);
  } else if (idx < 1705984) {                // inp init = x[511]: 512 x 128
    int i = idx - 1640448; outb[i] = f2b(x[33488896 + i]);
  } else if (idx < 1706240) {                // flags[16 groups][16 wgs]
    flags[idx - 1705984] = 0u;
  }
}

// Persistent decoder, grid = 256 x 256 threads (1 wg/CU, 4 waves = 1/SIMD).
// 16 groups x 16 wgs; group mb owns rows mb*32..+32, wg nb owns h-cols
// nb*32..+32. Wave wid owns BOTH: gate wid's 32x32 tile (k=640) AND the fc
// 32-out-col tile wid*32..+32 (k=512). Phase-1 amortizes each ds_read_b128
// A-fragment over TWO MFMAs (gate + fc) -> A-LDS-reads/CU-step 288 -> 160.
// Weights resident: 288 regs/lane (AGPR-backed at 1 wave/SIMD, 512-reg file).
// Per-wave poll+gather: wave wid polls its 4 flags (one vector load, __all)
// and stages h-cols wid*128..+128; stragglers block one wave, not the wg.
__global__ __launch_bounds__(256, 1) void decoder_persist(
    const u16* __restrict__ Wcat, const float* __restrict__ bsum,
    const u16* __restrict__ fcWb, const float* __restrict__ fcb,
    const float* __restrict__ c0,
    u16* __restrict__ hb0, u16* __restrict__ hb1, const u16* __restrict__ outb,
    float* __restrict__ dout, u32* __restrict__ flags)
{
  __shared__ __align__(16) u16  Alds[32 * AST];   // 32 x (512 h | 128 out | 8 pad)
  __shared__ __align__(16) float gbuf[4096];      // 4 gates x 32 x 32 exchange

  const int tid  = threadIdx.x;
  const int wid  = tid >> 6, lane = tid & 63;
  const int l31  = lane & 31, q2 = lane >> 5;     // MFMA: row/col = lane&31, k-grp = lane>>5
  const int mb   = blockIdx.x & 15;               // group (co-XCD under round-robin; perf-only)
  const int nb   = blockIdx.x >> 4;               // col-slice 0..15
  const int R    = mb * 32;
  u32* hf = flags + mb * 16;

  // ---- resident weights: gate tile 40 + fc tile 32 = 288 regs/lane ----
  v8s wfg[40];
  {
    const u16* wr = Wcat + (u64)(wid * 512 + nb * 32 + l31) * KK + q2 * 8;
    #pragma unroll
    for (int kc = 0; kc < 40; ++kc) wfg[kc] = *reinterpret_cast<const v8s*>(wr + kc * 16);
  }
  v8s wff[32];
  {
    const u16* fr = fcWb + (u64)(wid * 32 + l31) * H_ + q2 * 8;
    #pragma unroll
    for (int kc = 0; kc < 32; ++kc) wff[kc] = *reinterpret_cast<const v8s*>(fr + kc * 16);
  }

  const float bg = bsum[wid * 512 + nb * 32 + l31];
  const float bf = fcb[wid * 32 + l31];
  const int  fccol = wid * 32 + l31;
  const bool dopred = ((fccol >> 3) == nb);       // wg nb owns out-cols [8nb,8nb+8)

  // c state: 2 pairs/thread: (p*16+crow0, ccol..ccol+1) of wg's 32x32 h-tile
  const int crow0 = tid >> 4, ccol = (tid & 15) * 2;
  float cv[4];
  #pragma unroll
  for (int p = 0; p < 2; ++p) {
    int row = p * 16 + crow0;
    cv[2*p]   = c0[(R + row) * H_ + nb * 32 + ccol];
    cv[2*p+1] = c0[(R + row) * H_ + nb * 32 + ccol + 1];
  }

  const u16* hsrc = hb0;
  u16*       hdst = hb1;

  for (int t = 0; t <= NSTEP; ++t) {
    if (t > 0) {
      const u32 tt = (u32)t;
      for (;;) {                                  // wave polls its 4 slice flags
        u32 f = fpoll(hf + wid * 4 + (lane & 3));
        if (__all((int)(f >= tt))) break;
      }
      __asm__ volatile("" ::: "memory");
    }
    // ---- gather: wave wid stages h-cols wid*128..+128: 16 u64/lane ----
    {
      u64 tmp[16];
      #pragma unroll
      for (int k = 0; k < 16; ++k) {
        int v = k * 64 + lane;
        int row = v >> 5, c = v & 31;             // 32 u64 per 128-col row
        tmp[k] = ld64(hsrc + (R + row) * H_ + wid * 128 + c * 4);
      }
      #pragma unroll
      for (int k = 0; k < 16; ++k) {
        int v = k * 64 + lane;
        int row = v >> 5, c = v & 31;
        *reinterpret_cast<u64*>(&Alds[row * AST + wid * 128 + c * 4]) = tmp[k];
      }
    }
    if (t == 0) {                       // out(-1) = x[511] (preconverted)
      u64 tmp[4];
      #pragma unroll
      for (int k = 0; k < 4; ++k) {
        int v = k * 256 + tid;
        int row = v >> 5, c = v & 31;
        tmp[k] = ld64(outb + (R + row) * I_ + c * 4);
      }
      #pragma unroll
      for (int k = 0; k < 4; ++k) {
        int v = k * 256 + tid;
        int row = v >> 5, c = v & 31;
        *reinterpret_cast<u64*>(&Alds[row * AST + 512 + c * 4]) = tmp[k];
      }
    }
    __syncthreads();

    // ---- phase 1: k = 0..512; one A-read feeds gate AND fc MFMA ----
    v16f accg = {0.f,0.f,0.f,0.f,0.f,0.f,0.f,0.f,0.f,0.f,0.f,0.f,0.f,0.f,0.f,0.f};
    v16f accf = {0.f,0.f,0.f,0.f,0.f,0.f,0.f,0.f,0.f,0.f,0.f,0.f,0.f,0.f,0.f,0.f};
    const u16* ab = &Alds[l31 * AST + q2 * 8];
    #pragma unroll
    for (int kc = 0; kc < 32; ++kc) {
      v8s a = *reinterpret_cast<const v8s*>(ab + kc * 16);
      accg = __builtin_amdgcn_mfma_f32_32x32x16_bf16(a, wfg[kc], accg, 0, 0, 0);
      accf = __builtin_amdgcn_mfma_f32_32x32x16_bf16(a, wff[kc], accf, 0, 0, 0);
    }

    // ---- fc act: out(t-1) = 2*sigmoid(.)-1, feedback + dout ----
    if (t > 0) {
      float* dt = dout + (u64)(NSTEP - t) * (B_ * I_);
      #pragma unroll
      for (int r = 0; r < 16; ++r) {
        int row = (r & 3) + 8 * (r >> 2) + 4 * q2;   // 32x32 C-layout
        float o = 2.f / (1.f + __expf(-(accf[r] + bf))) - 1.f;
        Alds[row * AST + 512 + fccol] = f2b(o);
        if (dopred) __builtin_nontemporal_store(o, dt + (R + row) * I_ + fccol);
      }
    }
    __syncthreads();                    // out region ready

    if (t < NSTEP) {
      // ---- phase 2: k = 512..640 (out part) ----
      #pragma unroll
      for (int kc = 32; kc < 40; ++kc) {
        v8s a = *reinterpret_cast<const v8s*>(ab + kc * 16);
        accg = __builtin_amdgcn_mfma_f32_32x32x16_bf16(a, wfg[kc], accg, 0, 0, 0);
      }
      // ---- gate activation -> gbuf ----
      #pragma unroll
      for (int r = 0; r < 16; ++r) {
        int row = (r & 3) + 8 * (r >> 2) + 4 * q2;
        float z = accg[r] + bg;
        float a2 = (wid == 2) ? tanh_fast(z) : 1.f / (1.f + __expf(-z));
        gbuf[wid * 1024 + row * 32 + l31] = a2;
      }
      __syncthreads();

      // ---- cell: c in regs, h(t+1) packed u32 -> L3 ----
      #pragma unroll
      for (int p = 0; p < 2; ++p) {
        int row = p * 16 + crow0;
        int base = row * 32 + ccol;
        v2f ig = *reinterpret_cast<const v2f*>(&gbuf[       base]);
        v2f fg = *reinterpret_cast<const v2f*>(&gbuf[1024 + base]);
        v2f gg = *reinterpret_cast<const v2f*>(&gbuf[2048 + base]);
        v2f og = *reinterpret_cast<const v2f*>(&gbuf[3072 + base]);
        float cn0 = fg[0] * cv[2*p]   + ig[0] * gg[0];
        float cn1 = fg[1] * cv[2*p+1] + ig[1] * gg[1];
        cv[2*p] = cn0; cv[2*p+1] = cn1;
        u32 packed = (u32)f2b(og[0] * tanh_fast(cn0)) | ((u32)f2b(og[1] * tanh_fast(cn1)) << 16);
        st32(hdst + (R + row) * H_ + nb * 32 + ccol, packed);
      }
      __syncthreads();                  // vmcnt(0) drain: h stores acked at L3
      __asm__ volatile("" ::: "memory");
      if (tid == 0) fst(hf + nb, (u32)(t + 1));
    }

    { const u16* tp = hsrc; hsrc = hdst; hdst = (u16*)tp; }
  }
}

extern "C" void kernel_launch(void* const* d_in, const int* in_sizes, int n_in,
                              void* d_out, int out_size, void* d_ws, size_t ws_size,
                              hipStream_t stream)
{
  const float* x   = (const float*)d_in[0];
  // d_in[1] = enc_hiddens: unused by the reference
  const float* h0  = (const float*)d_in[2];
  const float* c0  = (const float*)d_in[3];
  const float* Wih = (const float*)d_in[4];
  const float* Whh = (const float*)d_in[5];
  const float* bih = (const float*)d_in[6];
  const float* bhh = (const float*)d_in[7];
  const float* fcW = (const float*)d_in[8];
  const float* fcb = (const float*)d_in[9];

  char* p = (char*)d_ws;
  u16*   Wcat  = (u16*)p;   p += 2048LL * 640 * 2;
  u16*   fcWb  = (u16*)p;   p += 128 * 512 * 2;
  float* bsum  = (float*)p; p += 2048 * 4;
  u16*   hb0   = (u16*)p;   p += 512 * 512 * 2;
  u16*   hb1   = (u16*)p;   p += 512 * 512 * 2;
  u16*   outb  = (u16*)p;   p += 512 * 128 * 2;
  u32*   flags = (u32*)p;   p += 256 * 4;
  float* dout  = (float*)d_out;

  init_kernel<<<6666, 256, 0, stream>>>(x, h0, Wih, Whh, bih, bhh, fcW,
                                        Wcat, fcWb, bsum, hb0, outb, flags);
  decoder_persist<<<256, 256, 0, stream>>>(Wcat, bsum, fcWb, fcb, c0,
                                           hb0, hb1, outb, dout, flags);
}

// Round 3
// 2770.194 us; speedup vs baseline: 1.1857x; 1.1857x over previous
//
#include <hip/hip_runtime.h>

typedef unsigned short u16;
typedef unsigned int   u32;
typedef unsigned long long u64;
typedef short v8s __attribute__((ext_vector_type(8)));
typedef float v16f __attribute__((ext_vector_type(16)));
typedef float v2f  __attribute__((ext_vector_type(2)));

#define B_ 512
#define I_ 128
#define H_ 512
#define KK 640
#define NSTEP 512
#define AST 648   // A-tile row stride, u16 elems (1296 B = 324 dw, 324%32=4 -> even bank spread)

__device__ inline u16 f2b(float x){
  union{float f; unsigned u;} v; v.f = x;
  unsigned r = v.u + 0x7fffu + ((v.u >> 16) & 1u);
  return (u16)(r >> 16);
}

// overflow-safe fast tanh: x->+inf => 1, x->-inf => -1 (exp underflow)
__device__ inline float tanh_fast(float x){
  float e = __expf(2.f * x);
  return 1.f - 2.f / (e + 1.f);
}

// All cross-wg traffic: relaxed agent-scope atomics -> L3 = coherence point.
__device__ inline u64 ld64(const u16* p){
  return __hip_atomic_load((const u64*)p, __ATOMIC_RELAXED, __HIP_MEMORY_SCOPE_AGENT);
}
__device__ inline void st32(u16* p, u32 v){
  __hip_atomic_store((u32*)p, v, __ATOMIC_RELAXED, __HIP_MEMORY_SCOPE_AGENT);
}
__device__ inline u32 fpoll(const u32* p){
  return __hip_atomic_load(p, __ATOMIC_RELAXED, __HIP_MEMORY_SCOPE_AGENT);
}
__device__ inline void fst(u32* p, u32 v){
  __hip_atomic_store(p, v, __ATOMIC_RELAXED, __HIP_MEMORY_SCOPE_AGENT);
}

// Prep: Wcat[gcol][k] = [W_hh (k<512) | W_ih (k>=512)] bf16, fcW bf16, fused
// bias, h0 bf16, out0 = x[511] bf16, zeroed flags. Re-runs every call.
__global__ void init_kernel(const float* __restrict__ x, const float* __restrict__ h0,
    const float* __restrict__ Wih, const float* __restrict__ Whh,
    const float* __restrict__ bih, const float* __restrict__ bhh, const float* __restrict__ fcW,
    u16* __restrict__ Wcat, u16* __restrict__ fcWb, float* __restrict__ bsum,
    u16* __restrict__ hb0, u16* __restrict__ outb, u32* __restrict__ flags)
{
  int idx = blockIdx.x * 256 + threadIdx.x;
  if (idx < 1310720) {                       // Wcat: 2048 x 640, [Whh | Wih]
    int g = idx / 640, k = idx - g * 640;
    float v = (k < 512) ? Whh[g * 512 + k] : Wih[g * 128 + (k - 512)];
    Wcat[idx] = f2b(v);
  } else if (idx < 1376256) {                // fcW bf16: 128 x 512
    int i = idx - 1310720; fcWb[i] = f2b(fcW[i]);
  } else if (idx < 1378304) {                // fused bias: 2048
    int i = idx - 1376256; bsum[i] = bih[i] + bhh[i];
  } else if (idx < 1640448) {                // h init: 512 x 512
    int i = idx - 1378304; hb0[i] = f2b(h0[i]);
  } else if (idx < 1705984) {                // inp init = x[511]: 512 x 128
    int i = idx - 1640448; outb[i] = f2b(x[33488896 + i]);
  } else if (idx < 1706240) {                // flags[16 groups][16 wgs]
    flags[idx - 1705984] = 0u;
  }
}

// Persistent decoder, grid = 256 x 512 threads (1 wg/CU, 8 waves = 2/SIMD).
// 16 groups x 16 wgs; group mb owns rows mb*32..+32, wg nb owns h-cols
// nb*32..+32. Waves 0-3: gate wid (i,f,g,o), 32x32 tile k=640. Waves 4-7:
// redundant local fc, out-cols (wid-4)*32..+32, k=512. Phase-1 (k<512) is
// the same loop for both roles.
// R3 deltas vs the 3071us kernel: (a) per-wave poll+gather (wave w polls only
// flags {2w,2w+1} covering its 64-col slice, then gathers immediately) -> one
// barrier removed, stragglers distributed; (b) dout stores deferred to the
// next iteration's poll/gather window (register-held) so their HBM ack never
// sits inside a barrier drain; (c) s_setprio(1) around the MFMA loops.
__global__ __launch_bounds__(512, 2) void decoder_persist(
    const u16* __restrict__ Wcat, const float* __restrict__ bsum,
    const u16* __restrict__ fcWb, const float* __restrict__ fcb,
    const float* __restrict__ c0,
    u16* __restrict__ hb0, u16* __restrict__ hb1, const u16* __restrict__ outb,
    float* __restrict__ dout, u32* __restrict__ flags)
{
  __shared__ __align__(16) u16  Alds[32 * AST];   // 32 x (512 h | 128 out | 8 pad)
  __shared__ __align__(16) float gbuf[4096];      // 4 gates x 32 x 32 exchange

  const int tid  = threadIdx.x;
  const int wid  = tid >> 6, lane = tid & 63;
  const int l31  = lane & 31, q2 = lane >> 5;     // MFMA: row/col = lane&31, k-grp = lane>>5
  const int mb   = blockIdx.x & 15;               // group (co-XCD under round-robin; perf-only)
  const int nb   = blockIdx.x >> 4;               // col-slice 0..15
  const int R    = mb * 32;
  u32* hf = flags + mb * 16;

  const bool isfc = (wid >= 4);
  const int  wc   = (wid - 4) * 32;               // fc out-col base (fc waves only)

  // ---- resident weights: 40 x v8s = 160 regs/lane (AGPR-backed) ----
  v8s wfrag[40];
  if (!isfc) {
    const u16* wr = Wcat + (u64)(wid * 512 + nb * 32 + l31) * KK + q2 * 8;
    #pragma unroll
    for (int kc = 0; kc < 40; ++kc) wfrag[kc] = *reinterpret_cast<const v8s*>(wr + kc * 16);
  } else {
    const u16* fr = fcWb + (u64)(wc + l31) * H_ + q2 * 8;
    #pragma unroll
    for (int kc = 0; kc < 32; ++kc) wfrag[kc] = *reinterpret_cast<const v8s*>(fr + kc * 16);
    #pragma unroll
    for (int kc = 32; kc < 40; ++kc) wfrag[kc] = (v8s){0,0,0,0,0,0,0,0};
  }
  const float bias0 = isfc ? fcb[wc + l31] : bsum[wid * 512 + nb * 32 + l31];

  // dout ownership: out-col (wc+l31) written by wg nb == col>>3 (8 cols/wg)
  const bool dopred = isfc && (((wc + l31) >> 3) == nb);

  // deferred dout state: 16 outputs of fc-act held in regs, flushed next iter
  float oreg[16];
  float* dpend = nullptr;

  // c state: 2 elems/thread: (crow, ccol..ccol+1) of the wg's 32x32 h-tile
  const int crow = tid >> 4, ccol = (tid * 2) & 31;
  float cv0 = c0[(R + crow) * H_ + nb * 32 + ccol];
  float cv1 = c0[(R + crow) * H_ + nb * 32 + ccol + 1];

  for (int t = 0; t <= NSTEP; ++t) {
    const u16* hsrc = (t & 1) ? hb1 : hb0;

    // ---- flush deferred dout (fire-and-forget; drains at post-gather bar,
    //      fully overlapped with the flag spin + gather latency) ----
    if (dopred && dpend) {
      #pragma unroll
      for (int r = 0; r < 16; ++r) {
        int row = (r & 3) + 8 * (r >> 2) + 4 * q2;
        __builtin_nontemporal_store(oreg[r], dpend + (R + row) * I_ + wc + l31);
      }
      dpend = nullptr;
    }

    // ---- per-wave poll: wave w needs slices {2w, 2w+1} for its gather ----
    if (t > 0) {
      const u32 tt = (u32)t;
      for (;;) {
        u32 f = fpoll(hf + 2 * wid + (lane & 1));
        if (__all((int)(f >= tt))) break;
      }
      __asm__ volatile("" ::: "memory");
    }

    // ---- gather: wave w stages h-cols [64w, 64w+64): 8 u64/lane ----
    {
      u64 tmp[8];
      #pragma unroll
      for (int k = 0; k < 8; ++k) {
        int v = k * 64 + lane;
        int row = v >> 4, c16 = v & 15;
        tmp[k] = ld64(hsrc + (R + row) * H_ + wid * 64 + c16 * 4);
      }
      #pragma unroll
      for (int k = 0; k < 8; ++k) {
        int v = k * 64 + lane;
        int row = v >> 4, c16 = v & 15;
        *reinterpret_cast<u64*>(&Alds[row * AST + wid * 64 + c16 * 4]) = tmp[k];
      }
    }
    if (t == 0) {                       // out(-1) = x[511] (preconverted)
      u64 tmp[2];
      #pragma unroll
      for (int u = 0; u < 2; ++u) {
        int v = u * 512 + tid;
        int row = v >> 5, cc = v & 31;
        tmp[u] = ld64(outb + (R + row) * I_ + cc * 4);
      }
      #pragma unroll
      for (int u = 0; u < 2; ++u) {
        int v = u * 512 + tid;
        int row = v >> 5, cc = v & 31;
        *reinterpret_cast<u64*>(&Alds[row * AST + 512 + cc * 4]) = tmp[u];
      }
    }
    __syncthreads();                    // bar A: full A-tile (h part) ready

    // ---- phase 1: k = 0..512 (h part), identical for gate and fc waves ----
    v16f acc = {0.f,0.f,0.f,0.f,0.f,0.f,0.f,0.f,0.f,0.f,0.f,0.f,0.f,0.f,0.f,0.f};
    const u16* ab = &Alds[l31 * AST + q2 * 8];
    __builtin_amdgcn_s_setprio(1);
    #pragma unroll
    for (int kc = 0; kc < 32; ++kc) {
      v8s a = *reinterpret_cast<const v8s*>(ab + kc * 16);
      acc = __builtin_amdgcn_mfma_f32_32x32x16_bf16(a, wfrag[kc], acc, 0, 0, 0);
    }
    __builtin_amdgcn_s_setprio(0);

    // ---- fc act: out(t-1) = 2*sigmoid(.)-1 -> LDS feedback + oreg ----
    if (isfc && t > 0) {
      #pragma unroll
      for (int r = 0; r < 16; ++r) {
        int row = (r & 3) + 8 * (r >> 2) + 4 * q2;   // 32x32 C-layout
        float o = 2.f / (1.f + __expf(-(acc[r] + bias0))) - 1.f;
        oreg[r] = o;
        Alds[row * AST + 512 + wc + l31] = f2b(o);
      }
      dpend = dout + (u64)(NSTEP - t) * (B_ * I_);
    }
    __syncthreads();                    // bar B: out region ready

    if (t < NSTEP) {
      if (!isfc) {
        // ---- phase 2: k = 512..640 (out part) ----
        __builtin_amdgcn_s_setprio(1);
        #pragma unroll
        for (int kc = 32; kc < 40; ++kc) {
          v8s a = *reinterpret_cast<const v8s*>(ab + kc * 16);
          acc = __builtin_amdgcn_mfma_f32_32x32x16_bf16(a, wfrag[kc], acc, 0, 0, 0);
        }
        __builtin_amdgcn_s_setprio(0);
        // ---- gate activation -> gbuf ----
        #pragma unroll
        for (int r = 0; r < 16; ++r) {
          int row = (r & 3) + 8 * (r >> 2) + 4 * q2;
          float z = acc[r] + bias0;
          float a2 = (wid == 2) ? tanh_fast(z) : 1.f / (1.f + __expf(-z));
          gbuf[wid * 1024 + row * 32 + l31] = a2;
        }
      }
      __syncthreads();                  // bar C: gbuf ready

      // ---- cell: c in regs, h(t+1) packed u32 -> L3 ----
      u16* hdst = (t & 1) ? hb0 : hb1;
      v2f ig = *reinterpret_cast<const v2f*>(&gbuf[       crow * 32 + ccol]);
      v2f fg = *reinterpret_cast<const v2f*>(&gbuf[1024 + crow * 32 + ccol]);
      v2f gg = *reinterpret_cast<const v2f*>(&gbuf[2048 + crow * 32 + ccol]);
      v2f og = *reinterpret_cast<const v2f*>(&gbuf[3072 + crow * 32 + ccol]);
      float cn0 = fg[0] * cv0 + ig[0] * gg[0];
      float cn1 = fg[1] * cv1 + ig[1] * gg[1];
      cv0 = cn0; cv1 = cn1;
      u32 packed = (u32)f2b(og[0] * tanh_fast(cn0)) | ((u32)f2b(og[1] * tanh_fast(cn1)) << 16);
      st32(hdst + (R + crow) * H_ + nb * 32 + ccol, packed);
      __syncthreads();                  // bar D: vmcnt(0) drain, h acked at L3
      __asm__ volatile("" ::: "memory");
      if (tid == 0) fst(hf + nb, (u32)(t + 1));
    }
  }

  // ---- final dout flush (out(511), computed at t = NSTEP) ----
  if (dopred && dpend) {
    #pragma unroll
    for (int r = 0; r < 16; ++r) {
      int row = (r & 3) + 8 * (r >> 2) + 4 * q2;
      __builtin_nontemporal_store(oreg[r], dpend + (R + row) * I_ + wc + l31);
    }
  }
}

extern "C" void kernel_launch(void* const* d_in, const int* in_sizes, int n_in,
                              void* d_out, int out_size, void* d_ws, size_t ws_size,
                              hipStream_t stream)
{
  const float* x   = (const float*)d_in[0];
  // d_in[1] = enc_hiddens: unused by the reference
  const float* h0  = (const float*)d_in[2];
  const float* c0  = (const float*)d_in[3];
  const float* Wih = (const float*)d_in[4];
  const float* Whh = (const float*)d_in[5];
  const float* bih = (const float*)d_in[6];
  const float* bhh = (const float*)d_in[7];
  const float* fcW = (const float*)d_in[8];
  const float* fcb = (const float*)d_in[9];

  char* p = (char*)d_ws;
  u16*   Wcat  = (u16*)p;   p += 2048LL * 640 * 2;
  u16*   fcWb  = (u16*)p;   p += 128 * 512 * 2;
  float* bsum  = (float*)p; p += 2048 * 4;
  u16*   hb0   = (u16*)p;   p += 512 * 512 * 2;
  u16*   hb1   = (u16*)p;   p += 512 * 512 * 2;
  u16*   outb  = (u16*)p;   p += 512 * 128 * 2;
  u32*   flags = (u32*)p;   p += 256 * 4;
  float* dout  = (float*)d_out;

  init_kernel<<<6666, 256, 0, stream>>>(x, h0, Wih, Whh, bih, bhh, fcW,
                                        Wcat, fcWb, bsum, hb0, outb, flags);
  decoder_persist<<<256, 512, 0, stream>>>(Wcat, bsum, fcWb, fcb, c0,
                                           hb0, hb1, outb, dout, flags);
}